// Round 4
// baseline (247.037 us; speedup 1.0000x reference)
//
#include <hip/hip_runtime.h>

// ArtNetwork: y = sigmoid(Wout @ tanh(W8 @ ... tanh(W1 @ tanh(Win@x+b)) ...))
// Design (R4):
//  - Hidden 16x16 layers via v_mfma_f32_16x16x16_f16 with A=W/4, B=h^T.
//    C/D layout (row=(lane>>4)*4+i, col=lane&15) == B layout (k=(lane>>4)*4+j,
//    n=lane&15): MFMA out -> tanh -> cvt_pkrtz -> next B frag. No LDS/shuffle.
//  - tanh in PACKED F32 (v_pk_fma_f32: 2 f32/lane per 2-cyc issue — this is
//    what the 157 TF f32 peak is made of). Pade(7,6) in zq=z/4 (scale folded
//    into weights), u=zq^2, with ONE v_rcp_f32 shared across the 4 tile values
//    via cross-multiplication. __builtin_elementwise_fma forces v_pk_fma.
//  - Output layer as a 17th MFMA: A = KOUT*Wout zero-padded to 16 rows; the 3
//    channels land in quad-0 lanes' acc[0..2]; masked sigmoid + 3 stores.
//    Removes all ds_swizzle/bpermute shuffles from the epilogue.
//  - 4096 blocks x 256 thr, launch_bounds(256,8); 2 tiles (32 pts)/wave-iter.

typedef float  f32x4 __attribute__((ext_vector_type(4)));
typedef float  f32x2 __attribute__((ext_vector_type(2)));
typedef __fp16 f16x4 __attribute__((ext_vector_type(4)));
typedef __fp16 f16x2 __attribute__((ext_vector_type(2)));

#define KOUT (-1.4426950408889634f) // -log2(e)
#define QSC  0.25f                  // weight pre-scale so MFMA emits z/4

// Packed-f32 tanh of 4 values. Inputs zq = z/4, |zq|<=1. Pade(7,6) in u=zq^2:
// tanh(4*zq) = zq*(4 + 8.205128u + 2.864339u^2 + 0.1212436u^3)
//                / (1 + 7.384615u + 5.967366u^2 + 0.8486901u^3)
// One rcp for all 4 denominators: r=rcp(qa.x*qa.y*qb.x*qb.y), then unwind.
__device__ __forceinline__ f16x4 tanh4(f32x2 za, f32x2 zb) {
    const f32x2 C0 = {4.0f, 4.0f};
    const f32x2 C1 = {8.2051282f, 8.2051282f};
    const f32x2 C2 = {2.8643390f, 2.8643390f};
    const f32x2 C3 = {0.12124357f, 0.12124357f};
    const f32x2 D1 = {7.3846154f, 7.3846154f};
    const f32x2 D2 = {5.9673662f, 5.9673662f};
    const f32x2 D3 = {0.84869012f, 0.84869012f};
    const f32x2 ONE = {1.0f, 1.0f};

    f32x2 ua = za * za;
    f32x2 ub = zb * zb;
    f32x2 pa = __builtin_elementwise_fma(ua, C3, C2);
    f32x2 pb = __builtin_elementwise_fma(ub, C3, C2);
    pa = __builtin_elementwise_fma(ua, pa, C1);
    pb = __builtin_elementwise_fma(ub, pb, C1);
    pa = __builtin_elementwise_fma(ua, pa, C0);
    pb = __builtin_elementwise_fma(ub, pb, C0);
    f32x2 qa = __builtin_elementwise_fma(ua, D3, D2);
    f32x2 qb = __builtin_elementwise_fma(ub, D3, D2);
    qa = __builtin_elementwise_fma(ua, qa, D1);
    qb = __builtin_elementwise_fma(ub, qb, D1);
    qa = __builtin_elementwise_fma(ua, qa, ONE);
    qb = __builtin_elementwise_fma(ub, qb, ONE);
    f32x2 na = za * pa;
    f32x2 nb = zb * pb;
    // shared reciprocal across 4 denominators (each q in [1, 15.2])
    float qqa = qa.x * qa.y;                 // <= 231
    float qqb = qb.x * qb.y;
    float r   = __builtin_amdgcn_rcpf(qqa * qqb);  // rcp of <= 5.4e4
    float ra  = r * qqb;                     // 1/(qa.x*qa.y)
    float rb  = r * qqa;                     // 1/(qb.x*qb.y)
    f32x2 rra = {ra, ra};
    f32x2 rrb = {rb, rb};
    f32x2 qas = {qa.y, qa.x};
    f32x2 qbs = {qb.y, qb.x};
    f32x2 ta = na * (rra * qas);             // {na.x/qa.x, na.y/qa.y}
    f32x2 tb = nb * (rrb * qbs);
    f16x2 lo = __builtin_amdgcn_cvt_pkrtz(ta.x, ta.y);
    f16x2 hi = __builtin_amdgcn_cvt_pkrtz(tb.x, tb.y);
    return __builtin_shufflevector(lo, hi, 0, 1, 2, 3);
}

__global__ __launch_bounds__(256, 8)
void artnet_kernel(const float2* __restrict__ x,     // [N][2]
                   const float2* __restrict__ Win,   // [16][2]
                   const float*  __restrict__ bin,   // [16]
                   const float4* __restrict__ Wh,    // [8][16][16]
                   const float4* __restrict__ Wout,  // [3][16]
                   float* __restrict__ out,          // [N][3]
                   int nPairs, int nWaves)
{
    const int tid  = blockIdx.x * 256 + threadIdx.x;
    const int gw   = tid >> 6;            // global wave id
    const int lane = threadIdx.x & 63;
    const int row  = lane & 15;           // m / point-col index
    const int quad = lane >> 4;           // 0..3

    // ---- Hidden-layer A fragments: A[m=row][k=quad*4+j] = W[l][row][k]/4
    f16x4 aw[8];
#pragma unroll
    for (int l = 0; l < 8; ++l) {
        float4 w = Wh[l * 64 + row * 4 + quad];
        f16x2 lo = __builtin_amdgcn_cvt_pkrtz(w.x * QSC, w.y * QSC);
        f16x2 hi = __builtin_amdgcn_cvt_pkrtz(w.z * QSC, w.w * QSC);
        aw[l] = __builtin_shufflevector(lo, hi, 0, 1, 2, 3);
    }

    // ---- Output-layer A fragment: rows 0..2 = KOUT*Wout[row], rows 3..15 = 0
    f16x4 awo = {(__fp16)0.0f, (__fp16)0.0f, (__fp16)0.0f, (__fp16)0.0f};
    if (row < 3) {
        float4 w = Wout[row * 4 + quad];
        f16x2 lo = __builtin_amdgcn_cvt_pkrtz(w.x * KOUT, w.y * KOUT);
        f16x2 hi = __builtin_amdgcn_cvt_pkrtz(w.z * KOUT, w.w * KOUT);
        awo = __builtin_shufflevector(lo, hi, 0, 1, 2, 3);
    }

    // ---- Input layer constants (features quad*4+j), pre-scaled by 1/4,
    //      packed as f32x2 pairs {feat 4q+0, 4q+1} and {4q+2, 4q+3}
    f32x2 w0a, w0b, w1a, w1b, bba, bbb;
    {
        float2 wr0 = Win[quad * 4 + 0], wr1 = Win[quad * 4 + 1];
        float2 wr2 = Win[quad * 4 + 2], wr3 = Win[quad * 4 + 3];
        w0a = (f32x2){wr0.x * QSC, wr1.x * QSC};
        w0b = (f32x2){wr2.x * QSC, wr3.x * QSC};
        w1a = (f32x2){wr0.y * QSC, wr1.y * QSC};
        w1b = (f32x2){wr2.y * QSC, wr3.y * QSC};
        bba = (f32x2){bin[quad * 4 + 0] * QSC, bin[quad * 4 + 1] * QSC};
        bbb = (f32x2){bin[quad * 4 + 2] * QSC, bin[quad * 4 + 3] * QSC};
    }

    const f32x4 zero4 = {0.0f, 0.0f, 0.0f, 0.0f};

    for (int pi = gw; pi < nPairs; pi += nWaves) {
        const int t0 = pi * 2;           // first tile of the pair
        f16x4 bf[2];

        // ---- Input layer: zq = (x @ Win^T + b)/4 via packed-f32 FMA
#pragma unroll
        for (int s = 0; s < 2; ++s) {
            float2 xv = x[(t0 + s) * 16 + row];
            f32x2 xx = {xv.x, xv.x};
            f32x2 yy = {xv.y, xv.y};
            f32x2 h01 = __builtin_elementwise_fma(xx, w0a, __builtin_elementwise_fma(yy, w1a, bba));
            f32x2 h23 = __builtin_elementwise_fma(xx, w0b, __builtin_elementwise_fma(yy, w1b, bbb));
            bf[s] = tanh4(h01, h23);
        }

        // ---- 8 hidden layers: MFMA (emits z/4) -> packed-f32 tanh -> next B
#pragma unroll
        for (int l = 0; l < 8; ++l) {
#pragma unroll
            for (int s = 0; s < 2; ++s) {
                f32x4 acc = __builtin_amdgcn_mfma_f32_16x16x16f16(aw[l], bf[s], zero4, 0, 0, 0);
                bf[s] = tanh4((f32x2){acc[0], acc[1]}, (f32x2){acc[2], acc[3]});
            }
        }

        // ---- Output layer as MFMA: acc rows 0..2 (quad 0) = KOUT*(Wout@h).
        //      sigmoid(z) = rcp(1 + exp2(KOUT*z)) on the 16 quad-0 lanes.
#pragma unroll
        for (int s = 0; s < 2; ++s) {
            f32x4 acco = __builtin_amdgcn_mfma_f32_16x16x16f16(awo, bf[s], zero4, 0, 0, 0);
            if (quad == 0) {
                const int p = (t0 + s) * 16 + row;
#pragma unroll
                for (int i = 0; i < 3; ++i) {
                    float e = __builtin_amdgcn_exp2f(acco[i]);
                    out[p * 3 + i] = __builtin_amdgcn_rcpf(e + 1.0f);
                }
            }
        }
    }
}

extern "C" void kernel_launch(void* const* d_in, const int* in_sizes, int n_in,
                              void* d_out, int out_size, void* d_ws, size_t ws_size,
                              hipStream_t stream) {
    const float2* x    = (const float2*)d_in[0];
    const float2* Win  = (const float2*)d_in[1];
    const float*  bin  = (const float*) d_in[2];
    const float4* Wh   = (const float4*)d_in[3];
    const float4* Wout = (const float4*)d_in[4];
    float* out = (float*)d_out;

    const int n      = in_sizes[0] / 2;   // 4,194,304 points
    const int nPairs = n / 32;            // 2 tiles of 16 points per wave-iter
    const int blocks = 4096;              // 64 waves/CU worth of work, 8 resident/SIMD
    const int nWaves = blocks * 4;

    artnet_kernel<<<blocks, 256, 0, stream>>>(x, Win, bin, Wh, Wout, out, nPairs, nWaves);
}

// Round 5
// 203.913 us; speedup vs baseline: 1.2115x; 1.2115x over previous
//
#include <hip/hip_runtime.h>

// ArtNetwork: y = sigmoid(Wout @ tanh(W8 @ ... tanh(W1 @ tanh(Win@x+b)) ...))
// Design (R5):
//  - All 9 layers + output as v_mfma_f32_16x16x16_f16, A=weights, B=h^T.
//    C/D layout == B layout => MFMA out -> tanh -> cvt_pkrtz -> next B frag.
//  - Input layer is an MFMA too: A=[K2*Win | K2*b | 0...], B={x,y,1,0} on quad0.
//  - tanh(z) = 1 - 2/(1+exp2(y)), y = 2*log2(e)*z (scale folded into weights so
//    MFMA emits y). ONE v_rcp_f32 per 4 values via product tree:
//    r = rcp(d0*d1*d2*d3), 1/di recovered with 2 muls each. Per 4 tanh:
//    5 trans-pipe ops (4 exp2 + 1 rcp) + 19 main-pipe ops. Trans pipe (1/4 rate)
//    and main VALU are separate pipes -> balanced ~800 cyc/iter each.
//  - Epilogue sigmoid: shared rcp across the 3 channels, KOUT folded into Wout.
//  - 4096 blocks x 256 thr (8 waves/SIMD for TLP), 2 tiles (32 pts)/wave-iter.

typedef float  f32x4 __attribute__((ext_vector_type(4)));
typedef __fp16 f16x4 __attribute__((ext_vector_type(4)));
typedef __fp16 f16x2 __attribute__((ext_vector_type(2)));

#define K2   2.8853900817779268f    // 2*log2(e): exp2(K2*z) = e^{2z}
#define KOUT (-1.4426950408889634f) // -log2(e):  exp2(KOUT*z) = e^{-z}

// tanh for 4 values from MFMA acc already scaled: y = 2*log2(e)*z.
// tanh = 1 - 2/(1+exp2(y)). One rcp for all four denominators.
__device__ __forceinline__ f16x4 tanh4s(f32x4 y) {
    float e0 = __builtin_amdgcn_exp2f(y[0]);
    float e1 = __builtin_amdgcn_exp2f(y[1]);
    float e2 = __builtin_amdgcn_exp2f(y[2]);
    float e3 = __builtin_amdgcn_exp2f(y[3]);
    float d0 = e0 + 1.0f, d1 = e1 + 1.0f, d2 = e2 + 1.0f, d3 = e3 + 1.0f;
    float p01 = d0 * d1, p23 = d2 * d3;           // d in [1,2981]: P<=7.9e13 ok
    float r   = __builtin_amdgcn_rcpf(p01 * p23);
    float i01 = r * p23, i23 = r * p01;           // 1/(d0*d1), 1/(d2*d3)
    float v0 = i01 * d1, v1 = i01 * d0;
    float v2 = i23 * d3, v3 = i23 * d2;           // 1/d_i
    float t0 = __builtin_fmaf(-2.0f, v0, 1.0f);
    float t1 = __builtin_fmaf(-2.0f, v1, 1.0f);
    float t2 = __builtin_fmaf(-2.0f, v2, 1.0f);
    float t3 = __builtin_fmaf(-2.0f, v3, 1.0f);
    f16x2 lo = __builtin_amdgcn_cvt_pkrtz(t0, t1);
    f16x2 hi = __builtin_amdgcn_cvt_pkrtz(t2, t3);
    return __builtin_shufflevector(lo, hi, 0, 1, 2, 3);
}

__global__ __launch_bounds__(256, 8)
void artnet_kernel(const float2* __restrict__ x,     // [N][2]
                   const float2* __restrict__ Win,   // [16][2]
                   const float*  __restrict__ bin,   // [16]
                   const float4* __restrict__ Wh,    // [8][16][16]
                   const float4* __restrict__ Wout,  // [3][16]
                   float* __restrict__ out,          // [N][3]
                   int nPairs, int nWaves)
{
    const int tid  = blockIdx.x * 256 + threadIdx.x;
    const int gw   = tid >> 6;            // global wave id
    const int lane = threadIdx.x & 63;
    const int row  = lane & 15;           // m / point-col index
    const int quad = lane >> 4;           // 0..3

    // ---- Hidden-layer A fragments: A[m=row][k=quad*4+j] = K2*W[l][row][k]
    f16x4 aw[8];
#pragma unroll
    for (int l = 0; l < 8; ++l) {
        float4 w = Wh[l * 64 + row * 4 + quad];
        f16x2 lo = __builtin_amdgcn_cvt_pkrtz(w.x * K2, w.y * K2);
        f16x2 hi = __builtin_amdgcn_cvt_pkrtz(w.z * K2, w.w * K2);
        aw[l] = __builtin_shufflevector(lo, hi, 0, 1, 2, 3);
    }

    // ---- Input-layer A fragment: k=0 -> K2*Win.x, k=1 -> K2*Win.y, k=2 -> K2*b
    f16x4 awin = {(__fp16)0.0f, (__fp16)0.0f, (__fp16)0.0f, (__fp16)0.0f};
    if (quad == 0) {
        float2 wr = Win[row];
        f16x2 lo = __builtin_amdgcn_cvt_pkrtz(wr.x * K2, wr.y * K2);
        f16x2 hi = __builtin_amdgcn_cvt_pkrtz(bin[row] * K2, 0.0f);
        awin = __builtin_shufflevector(lo, hi, 0, 1, 2, 3);
    }

    // ---- Output-layer A fragment: rows 0..2 = KOUT*Wout[row], rows 3..15 = 0
    f16x4 awo = {(__fp16)0.0f, (__fp16)0.0f, (__fp16)0.0f, (__fp16)0.0f};
    if (row < 3) {
        float4 w = Wout[row * 4 + quad];
        f16x2 lo = __builtin_amdgcn_cvt_pkrtz(w.x * KOUT, w.y * KOUT);
        f16x2 hi = __builtin_amdgcn_cvt_pkrtz(w.z * KOUT, w.w * KOUT);
        awo = __builtin_shufflevector(lo, hi, 0, 1, 2, 3);
    }

    const f32x4 zero4 = {0.0f, 0.0f, 0.0f, 0.0f};
    const f16x4 zb    = {(__fp16)0.0f, (__fp16)0.0f, (__fp16)0.0f, (__fp16)0.0f};

    for (int pi = gw; pi < nPairs; pi += nWaves) {
        const int t0 = pi * 2;           // first tile of the pair
        f16x4 bf[2];

        // ---- Input layer via MFMA: B = {x, y, 1, 0} on quad 0, else 0
#pragma unroll
        for (int s = 0; s < 2; ++s) {
            float2 xv = x[(t0 + s) * 16 + row];
            f16x2 lo = __builtin_amdgcn_cvt_pkrtz(xv.x, xv.y);
            f16x2 hi = {(__fp16)1.0f, (__fp16)0.0f};
            f16x4 bin_frag = __builtin_shufflevector(lo, hi, 0, 1, 2, 3);
            bf[s] = (quad == 0) ? bin_frag : zb;
        }
#pragma unroll
        for (int s = 0; s < 2; ++s) {
            f32x4 acc = __builtin_amdgcn_mfma_f32_16x16x16f16(awin, bf[s], zero4, 0, 0, 0);
            bf[s] = tanh4s(acc);
        }

        // ---- 8 hidden layers: MFMA (emits y=K2*z) -> shared-rcp tanh -> next B
#pragma unroll
        for (int l = 0; l < 8; ++l) {
#pragma unroll
            for (int s = 0; s < 2; ++s) {
                f32x4 acc = __builtin_amdgcn_mfma_f32_16x16x16f16(aw[l], bf[s], zero4, 0, 0, 0);
                bf[s] = tanh4s(acc);
            }
        }

        // ---- Output layer as MFMA: quad-0 lanes hold KOUT*(Wout@h) in acc[0..2].
        //      sigmoid = 1/(1+exp2(acco)); shared rcp across the 3 channels.
#pragma unroll
        for (int s = 0; s < 2; ++s) {
            f32x4 acco = __builtin_amdgcn_mfma_f32_16x16x16f16(awo, bf[s], zero4, 0, 0, 0);
            if (quad == 0) {
                const int p = (t0 + s) * 16 + row;
                float e0 = __builtin_amdgcn_exp2f(acco[0]);
                float e1 = __builtin_amdgcn_exp2f(acco[1]);
                float e2 = __builtin_amdgcn_exp2f(acco[2]);
                float d0 = e0 + 1.0f, d1 = e1 + 1.0f, d2 = e2 + 1.0f;
                float p01 = d0 * d1;
                float r   = __builtin_amdgcn_rcpf(p01 * d2);
                float s2  = r * p01;            // 1/d2
                float i01 = r * d2;             // 1/(d0*d1)
                float s0  = i01 * d1;           // 1/d0
                float s1  = i01 * d0;           // 1/d1
                out[p * 3 + 0] = s0;
                out[p * 3 + 1] = s1;
                out[p * 3 + 2] = s2;
            }
        }
    }
}

extern "C" void kernel_launch(void* const* d_in, const int* in_sizes, int n_in,
                              void* d_out, int out_size, void* d_ws, size_t ws_size,
                              hipStream_t stream) {
    const float2* x    = (const float2*)d_in[0];
    const float2* Win  = (const float2*)d_in[1];
    const float*  bin  = (const float*) d_in[2];
    const float4* Wh   = (const float4*)d_in[3];
    const float4* Wout = (const float4*)d_in[4];
    float* out = (float*)d_out;

    const int n      = in_sizes[0] / 2;   // 4,194,304 points
    const int nPairs = n / 32;            // 2 tiles of 16 points per wave-iter
    const int blocks = 4096;              // 16384 waves, 8/SIMD resident, 8 iters/wave
    const int nWaves = blocks * 4;

    artnet_kernel<<<blocks, 256, 0, stream>>>(x, Win, bin, Wh, Wout, out, nPairs, nWaves);
}

// Round 6
// 195.441 us; speedup vs baseline: 1.2640x; 1.0433x over previous
//
#include <hip/hip_runtime.h>

// ArtNetwork: y = sigmoid(Wout @ tanh(W8 @ ... tanh(W1 @ tanh(Win@x+b)) ...))
// Design (R6): propagate v = 1/(1+exp2(y)) instead of tanh(z).
//  Since tanh(z) = 1 - 2v, fold the affine part into the NEXT layer:
//    z' = W @ h = W·1 - 2·W@v  ->  A-frag = -2*K2*W, C-operand = K2*rowsum(W).
//  This removes 4 fma per tanh-quad; the MFMA C operand provides the bias free.
//  - All layers as v_mfma_f32_16x16x16_f16; C/D layout == B layout, so
//    MFMA out -> v4s -> cvt_pkrtz -> next B frag. No LDS, no shuffles in loop.
//  - v4s: 4 exp2 + 1 shared rcp (product tree) + 13 main ops + 2 cvt.
//  - Input layer: A=[K2*Win | K2*b | 0], B={x,y,1,*}; quad>0 lanes' B is
//    don't-care (A=0 there) -> no select needed.
//  - Output: A=-2*KOUT*Wout (3 rows), C=KOUT*rowsum(Wout); sigmoid on quad-0
//    lanes with ONE rcp shared across all 6 channel values (2 tiles x 3).
//  - 4096 blocks x 256 thr; 2 tiles (32 pts)/wave-iter; 8 iters/wave.

typedef float  f32x4 __attribute__((ext_vector_type(4)));
typedef __fp16 f16x4 __attribute__((ext_vector_type(4)));
typedef __fp16 f16x2 __attribute__((ext_vector_type(2)));

#define K2   2.8853900817779268f    // 2*log2(e): exp2(K2*z) = e^{2z}
#define KOUT (-1.4426950408889634f) // -log2(e):  exp2(KOUT*z) = e^{-z}

// v for 4 values: v_i = 1/(1+exp2(y_i)). One rcp via product tree.
// (tanh(z_i) = 1 - 2 v_i; the affine part is folded into the next layer.)
__device__ __forceinline__ f16x4 v4s(f32x4 y) {
    float e0 = __builtin_amdgcn_exp2f(y[0]);
    float e1 = __builtin_amdgcn_exp2f(y[1]);
    float e2 = __builtin_amdgcn_exp2f(y[2]);
    float e3 = __builtin_amdgcn_exp2f(y[3]);
    float d0 = e0 + 1.0f, d1 = e1 + 1.0f, d2 = e2 + 1.0f, d3 = e3 + 1.0f;
    float p01 = d0 * d1, p23 = d2 * d3;           // d in [1,2981]: prod <= 7.9e13
    float r   = __builtin_amdgcn_rcpf(p01 * p23);
    float i01 = r * p23, i23 = r * p01;           // 1/(d0*d1), 1/(d2*d3)
    float v0 = i01 * d1, v1 = i01 * d0;
    float v2 = i23 * d3, v3 = i23 * d2;           // 1/d_i
    f16x2 lo = __builtin_amdgcn_cvt_pkrtz(v0, v1);
    f16x2 hi = __builtin_amdgcn_cvt_pkrtz(v2, v3);
    return __builtin_shufflevector(lo, hi, 0, 1, 2, 3);
}

__global__ __launch_bounds__(256, 6)
void artnet_kernel(const float2* __restrict__ x,     // [N][2]
                   const float2* __restrict__ Win,   // [16][2]
                   const float*  __restrict__ bin,   // [16]
                   const float4* __restrict__ Wh,    // [8][16][16]
                   const float4* __restrict__ Wout,  // [3][16]
                   float* __restrict__ out,          // [N][3]
                   int nPairs, int nWaves)
{
    const int tid  = blockIdx.x * 256 + threadIdx.x;
    const int gw   = tid >> 6;            // global wave id
    const int lane = threadIdx.x & 63;
    const int row  = lane & 15;           // m / point-col index
    const int quad = lane >> 4;           // 0..3

    // ---- Hidden layers: A = -2*K2*W (f16), C = K2*rowsum(W) (f32, by C/D row)
    f16x4 aw[8];
    f32x4 crs[8];
#pragma unroll
    for (int l = 0; l < 8; ++l) {
        float4 w = Wh[l * 64 + row * 4 + quad];
        const float s = -2.0f * K2;
        f16x2 lo = __builtin_amdgcn_cvt_pkrtz(w.x * s, w.y * s);
        f16x2 hi = __builtin_amdgcn_cvt_pkrtz(w.z * s, w.w * s);
        aw[l] = __builtin_shufflevector(lo, hi, 0, 1, 2, 3);
        // rowsum(row) -> gather rowsums for C/D rows quad*4+i
        float partial = w.x + w.y + w.z + w.w;
        partial += __shfl_xor(partial, 16, 64);
        partial += __shfl_xor(partial, 32, 64);   // all quads of this row agree
        f32x4 c;
#pragma unroll
        for (int i = 0; i < 4; ++i)
            c[i] = K2 * __shfl(partial, quad * 4 + i, 64);
        crs[l] = c;
    }

    // ---- Input layer: A[m=row][k] = {K2*Win.x, K2*Win.y, K2*b, 0} on quad 0
    f16x4 awin = {(__fp16)0.0f, (__fp16)0.0f, (__fp16)0.0f, (__fp16)0.0f};
    if (quad == 0) {
        float2 wr = Win[row];
        f16x2 lo = __builtin_amdgcn_cvt_pkrtz(wr.x * K2, wr.y * K2);
        f16x2 hi = __builtin_amdgcn_cvt_pkrtz(bin[row] * K2, 0.0f);
        awin = __builtin_shufflevector(lo, hi, 0, 1, 2, 3);
    }

    // ---- Output layer: A = -2*KOUT*Wout (rows 0..2), C = KOUT*rowsum(Wout)
    f16x4 awo = {(__fp16)0.0f, (__fp16)0.0f, (__fp16)0.0f, (__fp16)0.0f};
    float prt = 0.0f;
    if (row < 3) {
        float4 w = Wout[row * 4 + quad];
        const float s = -2.0f * KOUT;
        f16x2 lo = __builtin_amdgcn_cvt_pkrtz(w.x * s, w.y * s);
        f16x2 hi = __builtin_amdgcn_cvt_pkrtz(w.z * s, w.w * s);
        awo = __builtin_shufflevector(lo, hi, 0, 1, 2, 3);
        prt = w.x + w.y + w.z + w.w;
    }
    prt += __shfl_xor(prt, 16, 64);
    prt += __shfl_xor(prt, 32, 64);
    f32x4 crso;
#pragma unroll
    for (int i = 0; i < 4; ++i)
        crso[i] = KOUT * __shfl(prt, quad * 4 + i, 64);

    const f32x4 zero4 = {0.0f, 0.0f, 0.0f, 0.0f};
    const f16x2 one0  = {(__fp16)1.0f, (__fp16)0.0f};

    for (int pi = gw; pi < nPairs; pi += nWaves) {
        const int t0 = pi * 2;           // first tile of the pair
        f16x4 bf[2];
        f32x4 acco[2];

        // ---- Input layer via MFMA: B = {x, y, 1, *}; quad>0 is don't-care.
#pragma unroll
        for (int s = 0; s < 2; ++s) {
            float2 xv = x[(t0 + s) * 16 + row];
            f16x2 lo = __builtin_amdgcn_cvt_pkrtz(xv.x, xv.y);
            bf[s] = __builtin_shufflevector(lo, one0, 0, 1, 2, 3);
        }
#pragma unroll
        for (int s = 0; s < 2; ++s) {
            f32x4 acc = __builtin_amdgcn_mfma_f32_16x16x16f16(awin, bf[s], zero4, 0, 0, 0);
            bf[s] = v4s(acc);
        }

        // ---- 8 hidden layers: MFMA emits y' = K2*(W·1 - 2W@v) directly
#pragma unroll
        for (int l = 0; l < 8; ++l) {
#pragma unroll
            for (int s = 0; s < 2; ++s) {
                f32x4 acc = __builtin_amdgcn_mfma_f32_16x16x16f16(aw[l], bf[s], crs[l], 0, 0, 0);
                bf[s] = v4s(acc);
            }
        }

        // ---- Output MFMA: quad-0 lanes hold KOUT*zout in acc[0..2]
#pragma unroll
        for (int s = 0; s < 2; ++s)
            acco[s] = __builtin_amdgcn_mfma_f32_16x16x16f16(awo, bf[s], crso, 0, 0, 0);

        // ---- Sigmoid epilogue: one rcp across 6 values (2 tiles x 3 channels)
        if (quad == 0) {
            float ea0 = __builtin_amdgcn_exp2f(acco[0][0]);
            float ea1 = __builtin_amdgcn_exp2f(acco[0][1]);
            float ea2 = __builtin_amdgcn_exp2f(acco[0][2]);
            float eb0 = __builtin_amdgcn_exp2f(acco[1][0]);
            float eb1 = __builtin_amdgcn_exp2f(acco[1][1]);
            float eb2 = __builtin_amdgcn_exp2f(acco[1][2]);
            float da0 = ea0 + 1.0f, da1 = ea1 + 1.0f, da2 = ea2 + 1.0f;
            float db0 = eb0 + 1.0f, db1 = eb1 + 1.0f, db2 = eb2 + 1.0f;
            float pa01 = da0 * da1, P3a = pa01 * da2;   // d <= 56: P6 <= 3.1e10
            float pb01 = db0 * db1, P3b = pb01 * db2;
            float r  = __builtin_amdgcn_rcpf(P3a * P3b);
            float rA = r * P3b, rB = r * P3a;           // 1/P3a, 1/P3b
            float sa2 = rA * pa01;                      // 1/da2
            float ia  = rA * da2;                       // 1/(da0*da1)
            float sa0 = ia * da1, sa1 = ia * da0;
            float sb2 = rB * pb01;
            float ib  = rB * db2;
            float sb0 = ib * db1, sb1 = ib * db0;
            const int p0 = t0 * 16 + row;
            out[p0 * 3 + 0] = sa0;
            out[p0 * 3 + 1] = sa1;
            out[p0 * 3 + 2] = sa2;
            const int p1 = p0 + 16;
            out[p1 * 3 + 0] = sb0;
            out[p1 * 3 + 1] = sb1;
            out[p1 * 3 + 2] = sb2;
        }
    }
}

extern "C" void kernel_launch(void* const* d_in, const int* in_sizes, int n_in,
                              void* d_out, int out_size, void* d_ws, size_t ws_size,
                              hipStream_t stream) {
    const float2* x    = (const float2*)d_in[0];
    const float2* Win  = (const float2*)d_in[1];
    const float*  bin  = (const float*) d_in[2];
    const float4* Wh   = (const float4*)d_in[3];
    const float4* Wout = (const float4*)d_in[4];
    float* out = (float*)d_out;

    const int n      = in_sizes[0] / 2;   // 4,194,304 points
    const int nPairs = n / 32;            // 2 tiles of 16 points per wave-iter
    const int blocks = 4096;              // 16384 waves, 8 iters/wave, no tail
    const int nWaves = blocks * 4;

    artnet_kernel<<<blocks, 256, 0, stream>>>(x, Win, bin, Wh, Wout, out, nPairs, nWaves);
}